// Round 7
// baseline (767.784 us; speedup 1.0000x reference)
//
#include <hip/hip_runtime.h>

namespace {

constexpr int TT = 1024;   // timesteps
constexpr int NB = 4096;   // batch
constexpr int H0 = 15, H1 = 10, H2 = 2;

// Pre-scales so activations use v_exp_f32 (exp2) directly:
// sigmoid(v) = 1/(1+exp2(-v*L2E)); tanh(u) = 2/(1+exp2(-u*2*L2E)) - 1.
constexpr float L2E  = 1.44269504088896340736f;
constexpr float L2E2 = 2.88539008177792681472f;

typedef float v2f __attribute__((ext_vector_type(2)));
typedef float v4f __attribute__((ext_vector_type(4)));

__device__ __forceinline__ float frcp(float v)  { return __builtin_amdgcn_rcpf(v); }
__device__ __forceinline__ float fexp2(float v) { return __builtin_amdgcn_exp2f(v); }
__device__ __forceinline__ float sigm_p(float v) { return frcp(1.0f + fexp2(-v)); }
__device__ __forceinline__ float tanh_p(float u) {
  return __builtin_fmaf(2.0f, frcp(1.0f + fexp2(-u)), -1.0f);
}
// In-place packed FMA / packed mul (chain head).
__device__ __forceinline__ void pk_fma(v2f& acc, v2f a, v2f b) {
  asm("v_pk_fma_f32 %0, %1, %2, %0" : "+v"(acc) : "v"(a), "v"(b));
}
__device__ __forceinline__ v2f pk_mul(v2f a, v2f b) {
  v2f d;
  asm("v_pk_mul_f32 %0, %1, %2" : "=v"(d) : "v"(a), "v"(b));
  return d;
}
// Pair combine: s + partner(lane^1) via DPP quad_perm [1,0,3,2] — VALU only,
// no DS pipe. Both lanes of the pair end with the full sum.
__device__ __forceinline__ float dpp_xor1_add(float s) {
  int p = __builtin_amdgcn_update_dpp(0, __builtin_bit_cast(int, s),
                                      0xB1 /*quad_perm 1,0,3,2*/, 0xF, 0xF, true);
  return s + __builtin_bit_cast(float, p);
}

// Window position p in [0,28) relative to the class's window start.
// g: 0=r, 1=z, 2=nx (input half of n), 3=nh (hidden half of n).
__device__ float wfetch(int c, int g, int u, int p,
                        const float* wi0, const float* wh0,
                        const float* wi1, const float* wh1,
                        const float* wi2, const float* wh2) {
  const int   gi = (g == 0) ? 0 : (g == 1) ? 1 : 2;
  const float sc = (g < 2) ? L2E : L2E2;
  if (c == 0) {            // window: x[0,5) .. h0[8,23)
    if (g != 3 && p < 5)             return wi0[(gi * H0 + u) * 5  + p]        * sc;
    if (g != 2 && p >= 8 && p < 23)  return wh0[(gi * H0 + u) * 15 + (p - 8)]  * sc;
  } else if (c == 1) {     // window: h0[0,15) .. h1[16,26)
    if (g != 3 && p < 15)            return wi1[(gi * H1 + u) * 15 + p]        * sc;
    if (g != 2 && p >= 16 && p < 26) return wh1[(gi * H1 + u) * 10 + (p - 16)] * sc;
  } else {                 // window: h1[0,10) .. h2[12,14)
    if (g != 3 && p < 10)            return wi2[(gi * H2 + u) * 10 + p]        * sc;
    if (g != 2 && p >= 12 && p < 14) return wh2[(gi * H2 + u) * 2  + (p - 12)] * sc;
  }
  return 0.0f;
}

}  // namespace

// Grid: 4096 blocks x 64 threads = 4 waves/SIMD (max occupancy for this
// recurrence). ONE sample per wave. Units get a PAIR of lanes: even half
// reads window floats [0,16), odd half [12,28) (ownership split at 14,
// zero-padded), 8-deep pk chains, partials merged with a DPP xor-1 add.
// Lane map: 0-53 = unit pairs (unit = lane>>1), 54-58 = x-loaders,
// 59-63 = unit-26 duplicates (publish to pad). Layers skewed
// (iter i: L0(i), L1(i-1), L2(i-2)) -> one publish per iteration.
// Single-wave block: no __syncthreads (in-order DS pipe); wave_barrier
// pins compiler ordering.
extern "C" __global__ __launch_bounds__(64, 4) void gru3_fused(
    const float* __restrict__ x,
    const float* __restrict__ w_ih0, const float* __restrict__ w_hh0,
    const float* __restrict__ b_ih0, const float* __restrict__ b_hh0,
    const float* __restrict__ w_ih1, const float* __restrict__ w_hh1,
    const float* __restrict__ b_ih1, const float* __restrict__ b_hh1,
    const float* __restrict__ w_ih2, const float* __restrict__ w_hh2,
    const float* __restrict__ b_ih2, const float* __restrict__ b_hh2,
    float* __restrict__ out) {
  // Staging (floats): x[0..4] pad[5..7] h0[8..22] pad[23] h1[24..33]
  // pad[34..35] h2[36..37] pad[38..55] (tail pad for odd-half L2 over-read).
  __shared__ __attribute__((aligned(16))) float stage[56];

  const int lane = threadIdx.x;   // single wave per block
  const int b    = blockIdx.x;    // sample

  // ---- lane roles ----
  int  unit, half;
  bool is_x = false;
  if (lane < 54)      { unit = lane >> 1;  half = lane & 1; }
  else if (lane < 59) { unit = 26;         half = lane & 1; is_x = true; }
  else                { unit = 26;         half = lane & 1; }   // dummy dup

  int c, u;
  if (unit < 15)      { c = 0; u = unit; }
  else if (unit < 25) { c = 1; u = unit - 15; }
  else                { c = 2; u = unit - 25; }

  const int  woff   = (c == 0) ? 0 : (c == 1) ? 8 : 24;
  const int  istart = c;                     // skew junk-suppression
  const bool is_o   = (lane < 54) && (c == 2) && (half == 0);
  const int  xj     = is_x ? (lane - 54) : 0;      // in-bounds x column
  // publish position
  int wpos;
  if (is_x)           wpos = xj;             // x(i+1)
  else if (lane >= 59) wpos = 38;            // pad (dummy)
  else                wpos = (c == 0) ? 8 + u : (c == 1) ? 24 + u : 36 + u;

  // ---- per-lane weights: 16 window floats (p = half*12 + j), ownership
  // split at window position 14 (even owns [0,14), odd owns [14,28)) ----
  float Wr[16], Wz[16], Wnx[16], Wnh[16];
#pragma unroll
  for (int j = 0; j < 16; ++j) {
    const int  p     = half * 12 + j;
    const bool owned = half ? (p >= 14) : (p < 14);
    Wr [j] = owned ? wfetch(c, 0, u, p, w_ih0, w_hh0, w_ih1, w_hh1, w_ih2, w_hh2) : 0.f;
    Wz [j] = owned ? wfetch(c, 1, u, p, w_ih0, w_hh0, w_ih1, w_hh1, w_ih2, w_hh2) : 0.f;
    Wnx[j] = owned ? wfetch(c, 2, u, p, w_ih0, w_hh0, w_ih1, w_hh1, w_ih2, w_hh2) : 0.f;
    Wnh[j] = owned ? wfetch(c, 3, u, p, w_ih0, w_hh0, w_ih1, w_hh1, w_ih2, w_hh2) : 0.f;
  }
  v2f Wr2[8], Wz2[8], Wnx2[8], Wnh2[8];
#pragma unroll
  for (int j = 0; j < 8; ++j) {
    Wr2 [j] = (v2f){Wr [2 * j], Wr [2 * j + 1]};
    Wz2 [j] = (v2f){Wz [2 * j], Wz [2 * j + 1]};
    Wnx2[j] = (v2f){Wnx[2 * j], Wnx[2 * j + 1]};
    Wnh2[j] = (v2f){Wnh[2 * j], Wnh[2 * j + 1]};
  }

  // biases (r,z folded; n halves separate)
  float br, bz, bnx, bnh;
  if (c == 0) {
    br  = (b_ih0[u] + b_hh0[u]) * L2E;
    bz  = (b_ih0[H0 + u] + b_hh0[H0 + u]) * L2E;
    bnx = b_ih0[2 * H0 + u] * L2E2;
    bnh = b_hh0[2 * H0 + u] * L2E2;
  } else if (c == 1) {
    br  = (b_ih1[u] + b_hh1[u]) * L2E;
    bz  = (b_ih1[H1 + u] + b_hh1[H1 + u]) * L2E;
    bnx = b_ih1[2 * H1 + u] * L2E2;
    bnh = b_hh1[2 * H1 + u] * L2E2;
  } else {
    br  = (b_ih2[u] + b_hh2[u]) * L2E;
    bz  = (b_ih2[H2 + u] + b_hh2[H2 + u]) * L2E;
    bnx = b_ih2[2 * H2 + u] * L2E2;
    bnh = b_hh2[2 * H2 + u] * L2E2;
  }

  // ---- init staging (zeros = h(-1)) and x pipeline (4-deep) ----
  for (int j = lane; j < 56; j += 64) stage[j] = 0.0f;

  float xw, xn, xf0, xf1;   // xw = x(i+1) published this iter
  {
    const size_t base = (size_t)b * 5 + xj;
    const float x0 = x[base];
    xw  = x[(size_t)1 * NB * 5 + base];
    xn  = x[(size_t)2 * NB * 5 + base];
    xf0 = x[(size_t)3 * NB * 5 + base];
    xf1 = x[(size_t)4 * NB * 5 + base];
    if (is_x) stage[xj] = x0;
  }
  __builtin_amdgcn_wave_barrier();

  float h = 0.0f;
  const v4f* wloc = (const v4f*)&stage[woff + half * 12];  // 16B-aligned
  float* pub = &stage[wpos];

  const float* xp = x + ((size_t)5 * NB + b) * 5 + xj;     // x(i+5)
  const size_t xstep = (size_t)NB * 5;
  float* op = out + (size_t)b * H2 + (is_o ? u : 0);       // t = i-2
  const size_t ostep = (size_t)NB * H2;

#pragma unroll 2
  for (int i = 0; i <= TT + 1; ++i) {
    // 16-float half-window (sees previous iteration's publishes)
    const v4f q0 = wloc[0], q1 = wloc[1], q2 = wloc[2], q3 = wloc[3];

    const float xldv = *xp;           // x(i+5), consumed 2 iters later
    if (i + 6 < TT) xp += xstep;      // uniform scalar condition

    v2f aR  = pk_mul(Wr2 [0], q0.lo);
    v2f aZ  = pk_mul(Wz2 [0], q0.lo);
    v2f aNx = pk_mul(Wnx2[0], q0.lo);
    v2f aNh = pk_mul(Wnh2[0], q0.lo);
#define GRU_DOT2(J, QH)           \
    pk_fma(aR,  Wr2 [J], (QH));   \
    pk_fma(aZ,  Wz2 [J], (QH));   \
    pk_fma(aNx, Wnx2[J], (QH));   \
    pk_fma(aNh, Wnh2[J], (QH));
    GRU_DOT2(1, q0.hi)
    GRU_DOT2(2, q1.lo)
    GRU_DOT2(3, q1.hi)
    GRU_DOT2(4, q2.lo)
    GRU_DOT2(5, q2.hi)
    GRU_DOT2(6, q3.lo)
    GRU_DOT2(7, q3.hi)
#undef GRU_DOT2

    // pair-combine (DPP, no DS) + bias
    const float sR  = dpp_xor1_add(aR.x  + aR.y)  + br;
    const float sZ  = dpp_xor1_add(aZ.x  + aZ.y)  + bz;
    const float sNx = dpp_xor1_add(aNx.x + aNx.y) + bnx;
    const float sNh = dpp_xor1_add(aNh.x + aNh.y) + bnh;

    const float r = sigm_p(sR);
    const float z = sigm_p(sZ);
    const float n = tanh_p(sNx + r * sNh);
    const float hnew = n + z * (h - n);
    h = (i >= istart) ? hnew : h;     // suppress before layer's first step

    *pub = is_x ? xw : h;             // publish h (units/dummies) or x(i+1)

    if (i >= 2) {                     // uniform branch
      if (is_o) *op = h;              // t = i-2, exec-masked
      op += ostep;
    }

    xw = xn; xn = xf0; xf0 = xf1; xf1 = xldv;   // rotate (renamed by unroll)
    __builtin_amdgcn_wave_barrier();  // next iter's reads after publishes
  }
}

extern "C" void kernel_launch(void* const* d_in, const int* in_sizes, int n_in,
                              void* d_out, int out_size, void* d_ws, size_t ws_size,
                              hipStream_t stream) {
  (void)in_sizes; (void)n_in; (void)d_ws; (void)ws_size; (void)out_size;
  const float* x     = (const float*)d_in[0];
  const float* w_ih0 = (const float*)d_in[1];
  const float* w_hh0 = (const float*)d_in[2];
  const float* b_ih0 = (const float*)d_in[3];
  const float* b_hh0 = (const float*)d_in[4];
  const float* w_ih1 = (const float*)d_in[5];
  const float* w_hh1 = (const float*)d_in[6];
  const float* b_ih1 = (const float*)d_in[7];
  const float* b_hh1 = (const float*)d_in[8];
  const float* w_ih2 = (const float*)d_in[9];
  const float* w_hh2 = (const float*)d_in[10];
  const float* b_ih2 = (const float*)d_in[11];
  const float* b_hh2 = (const float*)d_in[12];
  float* out = (float*)d_out;

  gru3_fused<<<NB, 64, 0, stream>>>(
      x, w_ih0, w_hh0, b_ih0, b_hh0,
      w_ih1, w_hh1, b_ih1, b_hh1,
      w_ih2, w_hh2, b_ih2, b_hh2, out);
}